// Round 3
// baseline (229.913 us; speedup 1.0000x reference)
//
#include <hip/hip_runtime.h>
#include <hip/hip_bf16.h>
#include <stdint.h>

// Problem constants (from reference)
#define T_DIM   4
#define N_GRID  12288
#define C_DIM   16
#define NH      9
#define N_OUT   1024        // UP*E
#define K_DIM   144         // NH*C
#define M_TOTAL 196608      // B*V*T*N_GRID
#define MG_ELEMS (8 * T_DIM * N_GRID * C_DIM)   // 6291456

typedef __attribute__((ext_vector_type(4)))  float    f32x4;
typedef __attribute__((ext_vector_type(16))) float    f32x16;
typedef __attribute__((ext_vector_type(4)))  _Float16 f16x4;
typedef __attribute__((ext_vector_type(8)))  _Float16 f16x8;

// ---------------------------------------------------------------------------
// Pre-pass 1: convert W (144x1024 f32) to f16, packed in MFMA B-fragment order
// for v_mfma_f32_32x32x16_f16.
//   Wpk element offset ((s*16+q)*64+lane)*16 + cg*8 + j =
//     f16( W[(16*s + 8*(lane>>5) + j) * 1024 + q*64 + cg*32 + (lane&31)] )
// s = K-step (0..8, = neighbor), q = 64-col group (0..15), cg = 32-col half.
// ---------------------------------------------------------------------------
__global__ void pack_w_kernel(const float* __restrict__ W,
                              _Float16* __restrict__ Wpk) {
    const int gid  = blockIdx.x * blockDim.x + threadIdx.x;  // 0..18431
    const int cg   = gid & 1;
    const int lane = (gid >> 1) & 63;
    const int q    = (gid >> 7) & 15;
    const int s    = gid >> 11;          // 0..8
    const int l31  = lane & 31;
    const int lhi  = lane >> 5;

    _Float16 v[8];
#pragma unroll
    for (int j = 0; j < 8; ++j) {
        const int k   = 16 * s + 8 * lhi + j;             // 0..143
        const int col = q * 64 + cg * 32 + l31;           // 0..1023
        v[j] = (_Float16)W[k * N_OUT + col];
    }
    *(f16x8*)(Wpk + (size_t)gid * 8) = *(const f16x8*)v;
}

// ---------------------------------------------------------------------------
// Pre-pass 2: convert mg_emb f32 -> f16 (same layout). 25 MB -> 12.6 MB.
// ---------------------------------------------------------------------------
__global__ void conv_mg_kernel(const float* __restrict__ mg,
                               _Float16* __restrict__ mgh) {
    const size_t n4 = MG_ELEMS / 4;
    const size_t stride = (size_t)gridDim.x * blockDim.x;
    for (size_t i = (size_t)blockIdx.x * blockDim.x + threadIdx.x; i < n4; i += stride) {
        f32x4 f = *(const f32x4*)(mg + 4 * i);
        f16x4 h;
#pragma unroll
        for (int j = 0; j < 4; ++j) h[j] = (_Float16)f[j];
        *(f16x4*)(mgh + 4 * i) = h;
    }
}

// ---------------------------------------------------------------------------
// Main kernel: barrier-free, LDS-free. One wave = 32 rows x 64 cols.
// Block = 256 threads (4 waves); grid = (M_TOTAL/32, 4).
// Wave w of block (x,y): rows [x*32, +32), col-group q = y*4 + w (64 cols).
// A-fragment gathered directly from pre-converted f16 mg via adjc.
// ---------------------------------------------------------------------------
__global__ __launch_bounds__(256, 4) void mg_gemm_kernel(
    const _Float16* __restrict__ mgh,   // (8, 4, 12288, 16) f16
    const int*   __restrict__ vidx,     // (1, 4)
    const int*   __restrict__ adjc,     // (12288, 9)
    const _Float16* __restrict__ Wpk,   // packed B fragments
    const float* __restrict__ bias,     // (1024,)
    float* __restrict__ out)            // (196608, 1024) f32
{
    const int rowtile = blockIdx.x;            // 0..6143
    const int tid  = threadIdx.x;
    const int w    = tid >> 6;                 // wave 0..3
    const int lane = tid & 63;
    const int l31  = lane & 31;
    const int lhi  = lane >> 5;
    const int q    = blockIdx.y * 4 + w;       // col-group 0..15

    const int r0 = rowtile * 32;
    const int v  = r0 / (T_DIM * N_GRID);
    const int t  = (r0 / N_GRID) & 3;
    const int p  = (r0 % N_GRID) + l31;        // this lane's grid point
    const int vi = vidx[v];
    const _Float16* src = mgh + (size_t)(vi * T_DIM + t) * N_GRID * C_DIM;

    // adjacency for this lane's row (lanes 32-63 duplicate 0-31; harmless)
    int g[NH];
#pragma unroll
    for (int s = 0; s < NH; ++s) g[s] = adjc[p * NH + s];

    const _Float16* wp = Wpk + ((size_t)q * 64 + lane) * 16;

    f32x16 acc0, acc1;
#pragma unroll
    for (int i = 0; i < 16; ++i) { acc0[i] = 0.f; acc1[i] = 0.f; }

#pragma unroll
    for (int s = 0; s < NH; ++s) {
        f16x8 a = *(const f16x8*)(src + (size_t)g[s] * C_DIM + 8 * lhi);
        const _Float16* bp = wp + (size_t)s * (16 * 64 * 16);
        f16x8 b0 = *(const f16x8*)(bp + 0);
        f16x8 b1 = *(const f16x8*)(bp + 8);
        acc0 = __builtin_amdgcn_mfma_f32_32x32x16_f16(a, b0, acc0, 0, 0, 0);
        acc1 = __builtin_amdgcn_mfma_f32_32x32x16_f16(a, b1, acc1, 0, 0, 0);
    }

    // ---- epilogue: add bias, non-temporal f32 stores ----
    const int colbase = q * 64 + l31;
    const float b0f = bias[colbase];
    const float b1f = bias[colbase + 32];
    float* outp = out + (size_t)r0 * N_OUT;

#pragma unroll
    for (int r = 0; r < 16; ++r) {
        const int rr = (r & 3) + 8 * (r >> 2) + 4 * lhi;   // 0..31
        __builtin_nontemporal_store(acc0[r] + b0f, &outp[(size_t)rr * N_OUT + colbase]);
        __builtin_nontemporal_store(acc1[r] + b1f, &outp[(size_t)rr * N_OUT + colbase + 32]);
    }
}

// ---------------------------------------------------------------------------
extern "C" void kernel_launch(void* const* d_in, const int* in_sizes, int n_in,
                              void* d_out, int out_size, void* d_ws, size_t ws_size,
                              hipStream_t stream) {
    const float* mg   = (const float*)d_in[0];   // mg_emb
    const int*   vidx = (const int*)  d_in[1];   // var_indices
    const int*   adjc = (const int*)  d_in[2];   // adjc
    const float* W    = (const float*)d_in[3];   // W
    const float* bias = (const float*)d_in[4];   // b
    float*       out  = (float*)d_out;

    _Float16* Wpk = (_Float16*)d_ws;                         // 294912 B
    _Float16* mgh = (_Float16*)((char*)d_ws + (1 << 20));    // 12.6 MB

    // pre-pack W into MFMA fragment order
    pack_w_kernel<<<dim3(72), dim3(256), 0, stream>>>(W, Wpk);
    // pre-convert mg_emb to f16
    conv_mg_kernel<<<dim3(1024), dim3(256), 0, stream>>>(mg, mgh);

    // main gather+GEMM: one wave per 32 rows x 64 cols
    mg_gemm_kernel<<<dim3(M_TOTAL / 32, 4), dim3(256), 0, stream>>>(
        mgh, vidx, adjc, Wpk, bias, out);
}